// Round 7
// baseline (252.971 us; speedup 1.0000x reference)
//
#include <hip/hip_runtime.h>
#include <hip/hip_bf16.h>

#define NN 10000
#define EE 65536

using short8  = __attribute__((ext_vector_type(8))) short;
using u16x8   = __attribute__((ext_vector_type(8))) unsigned short;
using float4v = __attribute__((ext_vector_type(4))) float;

__device__ __forceinline__ unsigned short f2b(float f){
  union { float f; unsigned int u; } v; v.f = f;
  unsigned int u = v.u;
  unsigned int r = (u + 0x7fff + ((u >> 16) & 1)) >> 16;  // RNE
  return (unsigned short)r;
}

// ---------------- prep: permB x2 (bf16 transposed weights) ----------------
// Bt[o][m*cin+i] = w2[m, i*64+o]

__device__ __forceinline__ void do_permB(int idx, const float* __restrict__ w2,
                                         unsigned short* __restrict__ Bt, int cin){
  int K = cin*64;
  int o = idx / K;
  int k = idx - o*K;
  int m = k / cin;
  int i = k - m*cin;
  Bt[idx] = f2b(w2[(size_t)m*(cin*64) + i*64 + o]);
}

__global__ __launch_bounds__(256) void k_prep(
    const float* __restrict__ w2a, unsigned short* __restrict__ Bt1,
    const float* __restrict__ w2b, unsigned short* __restrict__ Bt2){
  int b = blockIdx.x;
  int t = threadIdx.x;
  if(b < 256){
    do_permB(b*256 + t, w2a, Bt1, 16);
  } else {
    do_permB((b-256)*256 + t, w2b, Bt2, 64);
  }
}

// ---------------- single-block CSR build: histogram + scan + scatter ----------------

__global__ __launch_bounds__(1024) void k_csr(const int* __restrict__ dst,
    int* __restrict__ offs, int* __restrict__ elist){
  __shared__ int scnt[NN];            // 40 KB: counts -> cursors
  __shared__ int wsum[16];
  const int T = 1024, PER = (NN + T - 1)/T; // 10
  int tid = threadIdx.x;
  #pragma unroll
  for(int j=0;j<PER;j++){
    int i = tid*PER + j;
    if(i < NN) scnt[i] = 0;
  }
  __syncthreads();
  for(int e = tid; e < EE; e += T)
    atomicAdd(&scnt[dst[e]], 1);
  __syncthreads();
  int base = tid*PER;
  int local[PER];
  int s = 0;
  #pragma unroll
  for(int j=0;j<PER;j++){
    int i = base+j;
    int v = (i<NN)? scnt[i] : 0;
    local[j] = s;
    s += v;
  }
  int lane = tid & 63, wv = tid >> 6;
  int val = s;
  #pragma unroll
  for(int o=1;o<64;o<<=1){
    int u = __shfl_up(val, o, 64);
    if(lane >= o) val += u;
  }
  if(lane==63) wsum[wv] = val;
  __syncthreads();
  if(tid==0){
    int acc=0;
    #pragma unroll
    for(int i=0;i<16;i++){ int t2=wsum[i]; wsum[i]=acc; acc+=t2; }
  }
  __syncthreads();
  int thr_excl = wsum[wv] + (val - s);
  __syncthreads();
  #pragma unroll
  for(int j=0;j<PER;j++){
    int i = base+j;
    if(i<NN){ int e = thr_excl + local[j]; offs[i]=e; scnt[i]=e; }
  }
  if(tid == T-1) offs[NN] = thr_excl + s;
  __syncthreads();
  for(int e = tid; e < EE; e += T){
    int p = atomicAdd(&scnt[dst[e]], 1);
    elist[p] = e;
  }
}

// ---------------- per-dst rank-1 accumulation + inline edge-MLP, cin=16 ----------------

__global__ __launch_bounds__(64) void k_accK1(const float* __restrict__ x, const int* __restrict__ src,
    const int* __restrict__ offs, const int* __restrict__ elist,
    const float* __restrict__ ea, const float* __restrict__ w1, const float* __restrict__ b1,
    unsigned short* __restrict__ K1, float* __restrict__ XS, int v0){
  int v = v0 + blockIdx.x;
  int L = threadIdx.x;
  int cg = L & 3, mg = L >> 2;
  int i0 = cg << 2;
  float w1c0 = w1[L], w1c1 = w1[64+L], w1c2 = w1[128+L], w1c3 = w1[192+L];
  float b1c = b1[L];
  __shared__ float sh[2][64];
  float acc[4][4];
  #pragma unroll
  for(int j=0;j<4;j++)
    #pragma unroll
    for(int c=0;c<4;c++) acc[j][c]=0.f;
  float4 xs = make_float4(0.f,0.f,0.f,0.f);
  int p0 = offs[v], p1 = offs[v+1];
  float4 a_nxt = make_float4(0.f,0.f,0.f,0.f);
  float4 x_nxt = make_float4(0.f,0.f,0.f,0.f);
  if(p0 < p1){
    int e = elist[p0];
    a_nxt = *(const float4*)(ea + (size_t)e*4);
    x_nxt = *(const float4*)(x + (size_t)src[e]*16 + i0);
  }
  for(int p=p0;p<p1;p++){
    int buf = (p-p0)&1;
    float4 xv = x_nxt;
    float4 av = a_nxt;
    float hv = fmaxf(b1c + av.x*w1c0 + av.y*w1c1 + av.z*w1c2 + av.w*w1c3, 0.f);
    sh[buf][L] = hv;
    __syncthreads();
    if(p+1<p1){
      int e = elist[p+1];
      a_nxt = *(const float4*)(ea + (size_t)e*4);
      x_nxt = *(const float4*)(x + (size_t)src[e]*16 + i0);
    }
    xs.x += xv.x; xs.y += xv.y; xs.z += xv.z; xs.w += xv.w;
    #pragma unroll
    for(int j=0;j<4;j++){
      float hm = sh[buf][mg + 16*j];
      acc[j][0] += hm*xv.x; acc[j][1] += hm*xv.y;
      acc[j][2] += hm*xv.z; acc[j][3] += hm*xv.w;
    }
  }
  unsigned short* Kv = K1 + (size_t)blockIdx.x*1024;
  #pragma unroll
  for(int j=0;j<4;j++){
    int m = mg + 16*j;
    ushort4 u;
    u.x=f2b(acc[j][0]); u.y=f2b(acc[j][1]); u.z=f2b(acc[j][2]); u.w=f2b(acc[j][3]);
    *(ushort4*)(Kv + m*16 + i0) = u;
  }
  if(mg==0) *(float4*)(XS + (size_t)v*64 + i0) = xs;
}

// ---------------- per-dst rank-1 accumulation + inline edge-MLP, cin=64 ----------------

__global__ __launch_bounds__(64) void k_accK2(const float* __restrict__ x1, const int* __restrict__ src,
    const int* __restrict__ offs, const int* __restrict__ elist,
    const float* __restrict__ ea, const float* __restrict__ w1, const float* __restrict__ b1,
    unsigned short* __restrict__ K, float* __restrict__ XS, int v0){
  int v = v0 + blockIdx.x;
  int L = threadIdx.x;
  int cg = L & 7, mg = L >> 3;
  int i0 = cg << 3;
  float w1c0 = w1[L], w1c1 = w1[64+L], w1c2 = w1[128+L], w1c3 = w1[192+L];
  float b1c = b1[L];
  __shared__ float sh[2][64];
  float acc[8][8];
  #pragma unroll
  for(int j=0;j<8;j++)
    #pragma unroll
    for(int c=0;c<8;c++) acc[j][c]=0.f;
  float4 xs0 = make_float4(0.f,0.f,0.f,0.f);
  float4 xs1 = make_float4(0.f,0.f,0.f,0.f);
  int p0 = offs[v], p1 = offs[v+1];
  float4 a_nxt = make_float4(0.f,0.f,0.f,0.f);
  float4 x_nxt0 = make_float4(0.f,0.f,0.f,0.f);
  float4 x_nxt1 = make_float4(0.f,0.f,0.f,0.f);
  if(p0 < p1){
    int e = elist[p0];
    a_nxt = *(const float4*)(ea + (size_t)e*4);
    const float* xr = x1 + (size_t)src[e]*64 + i0;
    x_nxt0 = *(const float4*)xr;
    x_nxt1 = *(const float4*)(xr+4);
  }
  for(int p=p0;p<p1;p++){
    int buf = (p-p0)&1;
    float4 xv0 = x_nxt0, xv1 = x_nxt1;
    float4 av = a_nxt;
    float hv = fmaxf(b1c + av.x*w1c0 + av.y*w1c1 + av.z*w1c2 + av.w*w1c3, 0.f);
    sh[buf][L] = hv;
    __syncthreads();
    if(p+1<p1){
      int e = elist[p+1];
      a_nxt = *(const float4*)(ea + (size_t)e*4);
      const float* xr = x1 + (size_t)src[e]*64 + i0;
      x_nxt0 = *(const float4*)xr;
      x_nxt1 = *(const float4*)(xr+4);
    }
    xs0.x += xv0.x; xs0.y += xv0.y; xs0.z += xv0.z; xs0.w += xv0.w;
    xs1.x += xv1.x; xs1.y += xv1.y; xs1.z += xv1.z; xs1.w += xv1.w;
    float4 h4a = *(float4*)&sh[buf][mg*8];
    float4 h4b = *(float4*)&sh[buf][mg*8+4];
    #pragma unroll
    for(int jj=0;jj<2;jj++){
      float4 h4 = jj? h4b : h4a;
      #pragma unroll
      for(int tq=0;tq<4;tq++){
        int j = jj*4+tq;
        float hm = (tq==0)?h4.x:(tq==1)?h4.y:(tq==2)?h4.z:h4.w;
        acc[j][0] += hm*xv0.x; acc[j][1] += hm*xv0.y;
        acc[j][2] += hm*xv0.z; acc[j][3] += hm*xv0.w;
        acc[j][4] += hm*xv1.x; acc[j][5] += hm*xv1.y;
        acc[j][6] += hm*xv1.z; acc[j][7] += hm*xv1.w;
      }
    }
  }
  unsigned short* Kv = K + (size_t)blockIdx.x*4096;
  #pragma unroll
  for(int j=0;j<8;j++){
    int m = mg*8 + j;
    u16x8 u;
    #pragma unroll
    for(int c=0;c<8;c++) u[c] = f2b(acc[j][c]);
    *(u16x8*)(Kv + m*64 + i0) = u;
  }
  if(mg==0){
    *(float4*)(XS + (size_t)v*64 + i0)     = xs0;
    *(float4*)(XS + (size_t)v*64 + i0 + 4) = xs1;
  }
}

// ---------------- MFMA split-K GEMM with register-prefetch double buffering ----------------

#define GBK 64

__global__ __launch_bounds__(256) void k_gemm(const unsigned short* __restrict__ A,
    const unsigned short* __restrict__ Bt, float* __restrict__ P,
    int rows, int Ktot, int Kc){
  __shared__ unsigned short As[128*72];
  __shared__ unsigned short Bs[64*72];
  int t = threadIdx.x;
  int lane = t & 63;
  int w = t >> 6;
  int row0 = blockIdx.x*128;
  int k0 = blockIdx.y*Kc;

  int srow  = t >> 3;
  int skseg = (t & 7) << 3;

  float4v acc[2][4];
  #pragma unroll
  for(int rt=0;rt<2;rt++)
    #pragma unroll
    for(int ct=0;ct<4;ct++)
      #pragma unroll
      for(int qq=0;qq<4;qq++) acc[rt][ct][qq]=0.f;

  int lrow = lane & 15;
  int lk   = (lane >> 4) << 3;

  short8 a_pf[4], b_pf[2];
  int T = Kc/GBK;

  {
    int kk = k0 + skseg;
    #pragma unroll
    for(int qq=0;qq<4;qq++){
      int gr = row0 + srow + 32*qq;
      short8 z = {0,0,0,0,0,0,0,0};
      a_pf[qq] = (gr<rows)? *(const short8*)(A + (size_t)gr*Ktot + kk) : z;
    }
    #pragma unroll
    for(int qq=0;qq<2;qq++){
      int o = srow + 32*qq;
      b_pf[qq] = *(const short8*)(Bt + (size_t)o*Ktot + kk);
    }
  }

  for(int tt=0; tt<T; tt++){
    __syncthreads();
    #pragma unroll
    for(int qq=0;qq<4;qq++)
      *(short8*)(As + (srow + 32*qq)*72 + skseg) = a_pf[qq];
    #pragma unroll
    for(int qq=0;qq<2;qq++)
      *(short8*)(Bs + (srow + 32*qq)*72 + skseg) = b_pf[qq];
    __syncthreads();
    if(tt+1 < T){
      int kk = k0 + (tt+1)*GBK + skseg;
      #pragma unroll
      for(int qq=0;qq<4;qq++){
        int gr = row0 + srow + 32*qq;
        short8 z = {0,0,0,0,0,0,0,0};
        a_pf[qq] = (gr<rows)? *(const short8*)(A + (size_t)gr*Ktot + kk) : z;
      }
      #pragma unroll
      for(int qq=0;qq<2;qq++){
        int o = srow + 32*qq;
        b_pf[qq] = *(const short8*)(Bt + (size_t)o*Ktot + kk);
      }
    }
    #pragma unroll
    for(int k32=0;k32<2;k32++){
      int kf = k32*32 + lk;
      short8 a0 = *(short8*)(As + (w*32      + lrow)*72 + kf);
      short8 a1 = *(short8*)(As + (w*32 + 16 + lrow)*72 + kf);
      #pragma unroll
      for(int ct=0;ct<4;ct++){
        short8 b = *(short8*)(Bs + (ct*16 + lrow)*72 + kf);
        acc[0][ct] = __builtin_amdgcn_mfma_f32_16x16x32_bf16(a0, b, acc[0][ct], 0,0,0);
        acc[1][ct] = __builtin_amdgcn_mfma_f32_16x16x32_bf16(a1, b, acc[1][ct], 0,0,0);
      }
    }
  }
  size_t base = (size_t)blockIdx.y*rows*64;
  int quad = lane >> 4;
  #pragma unroll
  for(int rt=0;rt<2;rt++){
    #pragma unroll
    for(int ct=0;ct<4;ct++){
      int c = ct*16 + lrow;
      #pragma unroll
      for(int reg=0;reg<4;reg++){
        int r = row0 + w*32 + rt*16 + quad*4 + reg;
        if(r < rows) P[base + (size_t)r*64 + c] = acc[rt][ct][reg];
      }
    }
  }
}

// ---------------- split reduction + epilogue (layer1 / fallback) ----------------

template<int CIN, int SPLIT>
__global__ __launch_bounds__(256) void k_reduce_ep(const float* __restrict__ P, int rows, int v0,
    const float* __restrict__ XS, const float* __restrict__ b2, const float* __restrict__ xprev,
    const float* __restrict__ root, const float* __restrict__ bias, const int* __restrict__ offs,
    float* __restrict__ out){
  int idx = blockIdx.x*256 + threadIdx.x;
  if(idx >= rows*16) return;
  int r = idx >> 4, og = (idx & 15) << 2;
  int v = v0 + r;

  float4 s = make_float4(0.f,0.f,0.f,0.f);
  #pragma unroll
  for(int z=0; z<SPLIT; z++){
    float4 p = *(const float4*)(P + ((size_t)z*rows + r)*64 + og);
    s.x += p.x; s.y += p.y; s.z += p.z; s.w += p.w;
  }
  #pragma unroll
  for(int i=0;i<CIN;i++){
    float xsv = XS[(size_t)v*64 + i];
    float4 b = *(const float4*)(b2 + i*64 + og);
    s.x += xsv*b.x; s.y += xsv*b.y; s.z += xsv*b.z; s.w += xsv*b.w;
  }
  float4 rt = make_float4(0.f,0.f,0.f,0.f);
  #pragma unroll
  for(int i=0;i<CIN;i++){
    float xv = xprev[(size_t)v*CIN + i];
    float4 wv = *(const float4*)(root + i*64 + og);
    rt.x += xv*wv.x; rt.y += xv*wv.y; rt.z += xv*wv.z; rt.w += xv*wv.w;
  }
  float c = (float)(offs[v+1]-offs[v]); c = fmaxf(c, 1.f);
  float inv = 1.f/c;
  float4 bi = *(const float4*)(bias + og);
  float4 o;
  o.x = fmaxf(s.x*inv + rt.x + bi.x, 0.f);
  o.y = fmaxf(s.y*inv + rt.y + bi.y, 0.f);
  o.z = fmaxf(s.z*inv + rt.z + bi.z, 0.f);
  o.w = fmaxf(s.w*inv + rt.w + bi.w, 0.f);
  *(float4*)(out + (size_t)v*64 + og) = o;
}

// ---------------- layer-2 reduction + epilogue + fused readout ----------------

template<int SPLIT>
__global__ __launch_bounds__(256) void k_red2_ro(const float* __restrict__ P, int rows,
    const float* __restrict__ XS, const float* __restrict__ b2, const float* __restrict__ x1,
    const float* __restrict__ root, const float* __restrict__ bias, const int* __restrict__ offs,
    const float* __restrict__ lw1, const float* __restrict__ lb1,
    const float* __restrict__ lw2, const float* __restrict__ lb2,
    float* __restrict__ out){
  __shared__ float row[16][68];
  __shared__ float hjs[16][8];
  int tid = threadIdx.x;
  int idx = blockIdx.x*256 + tid;
  int r = idx >> 4, og = (idx & 15) << 2;
  int n = tid >> 4;
  int nbase = blockIdx.x*16;
  int ninblk = rows - nbase; if(ninblk > 16) ninblk = 16;

  float4 o = make_float4(0.f,0.f,0.f,0.f);
  if(r < rows){
    float4 s = make_float4(0.f,0.f,0.f,0.f);
    #pragma unroll
    for(int z=0; z<SPLIT; z++){
      float4 p = *(const float4*)(P + ((size_t)z*rows + r)*64 + og);
      s.x += p.x; s.y += p.y; s.z += p.z; s.w += p.w;
    }
    #pragma unroll
    for(int i=0;i<64;i++){
      float xsv = XS[(size_t)r*64 + i];
      float4 b = *(const float4*)(b2 + i*64 + og);
      s.x += xsv*b.x; s.y += xsv*b.y; s.z += xsv*b.z; s.w += xsv*b.w;
    }
    float4 rt = make_float4(0.f,0.f,0.f,0.f);
    #pragma unroll
    for(int i=0;i<64;i++){
      float xv = x1[(size_t)r*64 + i];
      float4 wv = *(const float4*)(root + i*64 + og);
      rt.x += xv*wv.x; rt.y += xv*wv.y; rt.z += xv*wv.z; rt.w += xv*wv.w;
    }
    float c = (float)(offs[r+1]-offs[r]); c = fmaxf(c, 1.f);
    float inv = 1.f/c;
    float4 bi = *(const float4*)(bias + og);
    o.x = fmaxf(s.x*inv + rt.x + bi.x, 0.f);
    o.y = fmaxf(s.y*inv + rt.y + bi.y, 0.f);
    o.z = fmaxf(s.z*inv + rt.z + bi.z, 0.f);
    o.w = fmaxf(s.w*inv + rt.w + bi.w, 0.f);
  }
  *(float4*)&row[n][og] = o;
  __syncthreads();
  if(tid < 128){
    int n2 = tid >> 3, j = tid & 7;
    if(n2 < ninblk){
      float a = lb1[j];
      #pragma unroll
      for(int i=0;i<64;i++) a += row[n2][i]*lw1[i*8+j];
      hjs[n2][j] = fmaxf(a, 0.f)*lw2[j];
    }
  }
  __syncthreads();
  if(tid < 16 && tid < ninblk){
    float s = lb2[0];
    #pragma unroll
    for(int j=0;j<8;j++) s += hjs[tid][j];
    out[nbase + tid] = s;
  }
}

// ---------------- readout (fallback path only) ----------------

__global__ void k_readout(const float* __restrict__ x2, const float* __restrict__ lw1,
                          const float* __restrict__ lb1, const float* __restrict__ lw2,
                          const float* __restrict__ lb2, float* __restrict__ out){
  int v = blockIdx.x*256 + threadIdx.x;
  if(v >= NN) return;
  float accj[8];
  #pragma unroll
  for(int j=0;j<8;j++) accj[j] = lb1[j];
  const float* xr = x2 + (size_t)v*64;
  #pragma unroll 16
  for(int i=0;i<64;i++){
    float xv = xr[i];
    #pragma unroll
    for(int j=0;j<8;j++) accj[j] += xv*lw1[i*8+j];
  }
  float o = lb2[0];
  #pragma unroll
  for(int j=0;j<8;j++) o += fmaxf(accj[j],0.f)*lw2[j];
  out[v] = o;
}

// ---------------- host ----------------

extern "C" void kernel_launch(void* const* d_in, const int* in_sizes, int n_in,
                              void* d_out, int out_size, void* d_ws, size_t ws_size,
                              hipStream_t stream) {
  const float* x      = (const float*)d_in[0];
  const int*   ei     = (const int*)d_in[1];
  const float* ea     = (const float*)d_in[2];
  const float* nn1_w1 = (const float*)d_in[3];
  const float* nn1_b1 = (const float*)d_in[4];
  const float* nn1_w2 = (const float*)d_in[5];
  const float* nn1_b2 = (const float*)d_in[6];
  const float* root1  = (const float*)d_in[7];
  const float* bias1  = (const float*)d_in[8];
  const float* nn2_w1 = (const float*)d_in[9];
  const float* nn2_b1 = (const float*)d_in[10];
  const float* nn2_w2 = (const float*)d_in[11];
  const float* nn2_b2 = (const float*)d_in[12];
  const float* root2  = (const float*)d_in[13];
  const float* bias2  = (const float*)d_in[14];
  const float* lin1_w = (const float*)d_in[15];
  const float* lin1_b = (const float*)d_in[16];
  const float* lin2_w = (const float*)d_in[17];
  const float* lin2_b = (const float*)d_in[18];
  float* out = (float*)d_out;

  const int* srcIdx = ei;
  const int* dstIdx = ei + EE;

  char* w = (char*)d_ws;
  size_t off = 0;
  auto alloc = [&](size_t bytes)->void*{
    void* p = w + off;
    off = (off + bytes + 255) & ~(size_t)255;
    return p;
  };
  int*            offs   = (int*)           alloc((size_t)(NN+1)*4);
  int*            elist  = (int*)           alloc((size_t)EE*4);
  float*          XS     = (float*)         alloc((size_t)NN*64*4);
  float*          x1     = (float*)         alloc((size_t)NN*64*4);
  unsigned short* Bt1    = (unsigned short*)alloc((size_t)64*1024*2);
  unsigned short* Bt2    = (unsigned short*)alloc((size_t)64*4096*2);
  size_t fixedBytes = off;
  size_t R = (ws_size > fixedBytes) ? (ws_size - fixedBytes) : 0;

  const int S1 = 4, S2 = 8;
  size_t needSingle = (size_t)NN*4096*2 + (size_t)S2*NN*64*4;
  bool single = (R >= needSingle + 4096);

  k_prep<<<1280, 256, 0, stream>>>(nn1_w2, Bt1, nn2_w2, Bt2);
  k_csr <<<1, 1024, 0, stream>>>(dstIdx, offs, elist);

  if(single){
    unsigned short* Kbuf = (unsigned short*)(w + off);
    float* P = (float*)(w + off + (size_t)NN*4096*2);

    k_accK1<<<NN, 64, 0, stream>>>(x, srcIdx, offs, elist, ea, nn1_w1, nn1_b1, Kbuf, XS, 0);
    {
      dim3 g((NN+127)/128, S1);
      k_gemm<<<g, 256, 0, stream>>>(Kbuf, Bt1, P, NN, 1024, 1024/S1);
    }
    k_reduce_ep<16,S1><<<(NN*16+255)/256, 256, 0, stream>>>(P, NN, 0, XS, nn1_b2, x,
                                                             root1, bias1, offs, x1);
    k_accK2<<<NN, 64, 0, stream>>>(x1, srcIdx, offs, elist, ea, nn2_w1, nn2_b1, Kbuf, XS, 0);
    {
      dim3 g((NN+127)/128, S2);
      k_gemm<<<g, 256, 0, stream>>>(Kbuf, Bt2, P, NN, 4096, 4096/S2);
    }
    k_red2_ro<S2><<<(NN+15)/16, 256, 0, stream>>>(P, NN, XS, nn2_b2, x1, root2, bias2, offs,
                                                   lin1_w, lin1_b, lin2_w, lin2_b, out);
  } else {
    float* x2b = (float*)alloc((size_t)NN*64*4);
    R = (ws_size > off) ? (ws_size - off) : 0;
    long long C2 = (long long)(R / (4096*2 + S2*64*4));
    long long C1 = (long long)(R / (1024*2 + S1*64*4));
    if(C2 > NN) C2 = NN; if(C1 > NN) C1 = NN;
    if(C2 < 128) C2 = 128; if(C1 < 128) C1 = 128;
    unsigned short* Kbuf = (unsigned short*)(w + off);
    {
      float* P = (float*)(w + off + (size_t)C1*1024*2);
      for(long long v0=0; v0<NN; v0+=C1){
        int rows = (int)((NN - v0 < C1) ? (NN - v0) : C1);
        k_accK1<<<rows, 64, 0, stream>>>(x, srcIdx, offs, elist, ea, nn1_w1, nn1_b1, Kbuf, XS, (int)v0);
        dim3 g((rows+127)/128, S1);
        k_gemm<<<g, 256, 0, stream>>>(Kbuf, Bt1, P, rows, 1024, 1024/S1);
        k_reduce_ep<16,S1><<<(rows*16+255)/256, 256, 0, stream>>>(P, rows, (int)v0, XS, nn1_b2, x,
                                                                   root1, bias1, offs, x1);
      }
    }
    {
      float* P = (float*)(w + off + (size_t)C2*4096*2);
      for(long long v0=0; v0<NN; v0+=C2){
        int rows = (int)((NN - v0 < C2) ? (NN - v0) : C2);
        k_accK2<<<rows, 64, 0, stream>>>(x1, srcIdx, offs, elist, ea, nn2_w1, nn2_b1, Kbuf, XS, (int)v0);
        dim3 g((rows+127)/128, S2);
        k_gemm<<<g, 256, 0, stream>>>(Kbuf, Bt2, P, rows, 4096, 4096/S2);
        k_reduce_ep<64,S2><<<(rows*16+255)/256, 256, 0, stream>>>(P, rows, (int)v0, XS, nn2_b2, x1,
                                                                   root2, bias2, offs, x2b);
      }
    }
    k_readout<<<(NN+255)/256, 256, 0, stream>>>(x2b, lin1_w, lin1_b, lin2_w, lin2_b, out);
  }
}

// Round 8
// 211.568 us; speedup vs baseline: 1.1957x; 1.1957x over previous
//
#include <hip/hip_runtime.h>
#include <hip/hip_bf16.h>

#define NN 10000
#define EE 65536

using short8  = __attribute__((ext_vector_type(8))) short;
using u16x8   = __attribute__((ext_vector_type(8))) unsigned short;
using float4v = __attribute__((ext_vector_type(4))) float;

__device__ __forceinline__ unsigned short f2b(float f){
  union { float f; unsigned int u; } v; v.f = f;
  unsigned int u = v.u;
  unsigned int r = (u + 0x7fff + ((u >> 16) & 1)) >> 16;  // RNE
  return (unsigned short)r;
}

// ---------------- prep: zero cnt + permB x2 (bf16 transposed weights) ----------------
// blocks: [0,40) zero cnt | [40,296) permB1 | [296,1320) permB2

__device__ __forceinline__ void do_permB(int idx, const float* __restrict__ w2,
                                         unsigned short* __restrict__ Bt, int cin){
  int K = cin*64;
  int o = idx / K;
  int k = idx - o*K;
  int m = k / cin;
  int i = k - m*cin;
  Bt[idx] = f2b(w2[(size_t)m*(cin*64) + i*64 + o]);
}

__global__ __launch_bounds__(256) void k_prep(
    const float* __restrict__ w2a, unsigned short* __restrict__ Bt1,
    const float* __restrict__ w2b, unsigned short* __restrict__ Bt2,
    int* __restrict__ cnt){
  int b = blockIdx.x;
  int t = threadIdx.x;
  if(b < 40){
    int i = b*256 + t;
    if(i < NN) cnt[i] = 0;
  } else if(b < 296){
    do_permB((b-40)*256 + t, w2a, Bt1, 16);
  } else {
    do_permB((b-296)*256 + t, w2b, Bt2, 64);
  }
}

// ---------------- CSR build (multi-block: parallelism >> dispatch count) ----------------

__global__ void k_hist(const int* __restrict__ dst, int* __restrict__ cnt){
  int e = blockIdx.x*256 + threadIdx.x;
  if(e < EE) atomicAdd(&cnt[dst[e]], 1);
}

__global__ __launch_bounds__(1024) void k_scan(const int* __restrict__ cnt, int* __restrict__ offs, int* __restrict__ cursor){
  const int T = 1024, PER = (NN + T - 1)/T; // 10
  int tid = threadIdx.x;
  int base = tid*PER;
  int local[PER];
  int s = 0;
  #pragma unroll
  for(int j=0;j<PER;j++){
    int i = base+j;
    int v = (i<NN)? cnt[i] : 0;
    local[j] = s;
    s += v;
  }
  int lane = tid & 63, wv = tid >> 6;
  int val = s;
  #pragma unroll
  for(int o=1;o<64;o<<=1){
    int u = __shfl_up(val, o, 64);
    if(lane >= o) val += u;
  }
  __shared__ int wsum[16];
  if(lane==63) wsum[wv] = val;
  __syncthreads();
  if(tid==0){
    int acc=0;
    #pragma unroll
    for(int i=0;i<16;i++){ int t2=wsum[i]; wsum[i]=acc; acc+=t2; }
  }
  __syncthreads();
  int thr_excl = wsum[wv] + (val - s);
  #pragma unroll
  for(int j=0;j<PER;j++){
    int i = base+j;
    if(i<NN){ int e = thr_excl + local[j]; offs[i]=e; cursor[i]=e; }
  }
  if(tid == T-1) offs[NN] = thr_excl + s;
}

__global__ void k_scatter(const int* __restrict__ dst, int* __restrict__ cursor, int* __restrict__ elist){
  int e = blockIdx.x*256 + threadIdx.x;
  if(e < EE){ int p = atomicAdd(&cursor[dst[e]], 1); elist[p] = e; }
}

// ---------------- per-dst rank-1 accumulation + inline edge-MLP, cin=16 ----------------
// lane L: cg=L&3 (cols i0=cg*4..+3), mg=L>>2, m = mg + 16j.
// h[e][L] computed inline: relu(b1[L] + sum_d ea[e][d]*w1[d*64+L]).

__global__ __launch_bounds__(64) void k_accK1(const float* __restrict__ x, const int* __restrict__ src,
    const int* __restrict__ offs, const int* __restrict__ elist,
    const float* __restrict__ ea, const float* __restrict__ w1, const float* __restrict__ b1,
    unsigned short* __restrict__ K1, float* __restrict__ XS, int v0){
  int v = v0 + blockIdx.x;
  int L = threadIdx.x;
  int cg = L & 3, mg = L >> 2;
  int i0 = cg << 2;
  float w1c0 = w1[L], w1c1 = w1[64+L], w1c2 = w1[128+L], w1c3 = w1[192+L];
  float b1c = b1[L];
  __shared__ float sh[2][64];
  float acc[4][4];
  #pragma unroll
  for(int j=0;j<4;j++)
    #pragma unroll
    for(int c=0;c<4;c++) acc[j][c]=0.f;
  float4 xs = make_float4(0.f,0.f,0.f,0.f);
  int p0 = offs[v], p1 = offs[v+1];
  float4 a_nxt = make_float4(0.f,0.f,0.f,0.f);
  float4 x_nxt = make_float4(0.f,0.f,0.f,0.f);
  if(p0 < p1){
    int e = elist[p0];
    a_nxt = *(const float4*)(ea + (size_t)e*4);
    x_nxt = *(const float4*)(x + (size_t)src[e]*16 + i0);
  }
  for(int p=p0;p<p1;p++){
    int buf = (p-p0)&1;
    float4 xv = x_nxt;
    float4 av = a_nxt;
    float hv = fmaxf(b1c + av.x*w1c0 + av.y*w1c1 + av.z*w1c2 + av.w*w1c3, 0.f);
    sh[buf][L] = hv;
    __syncthreads();
    if(p+1<p1){
      int e = elist[p+1];
      a_nxt = *(const float4*)(ea + (size_t)e*4);
      x_nxt = *(const float4*)(x + (size_t)src[e]*16 + i0);
    }
    xs.x += xv.x; xs.y += xv.y; xs.z += xv.z; xs.w += xv.w;
    #pragma unroll
    for(int j=0;j<4;j++){
      float hm = sh[buf][mg + 16*j];
      acc[j][0] += hm*xv.x; acc[j][1] += hm*xv.y;
      acc[j][2] += hm*xv.z; acc[j][3] += hm*xv.w;
    }
  }
  unsigned short* Kv = K1 + (size_t)blockIdx.x*1024;
  #pragma unroll
  for(int j=0;j<4;j++){
    int m = mg + 16*j;
    ushort4 u;
    u.x=f2b(acc[j][0]); u.y=f2b(acc[j][1]); u.z=f2b(acc[j][2]); u.w=f2b(acc[j][3]);
    *(ushort4*)(Kv + m*16 + i0) = u;
  }
  if(mg==0) *(float4*)(XS + (size_t)v*64 + i0) = xs;
}

// ---------------- per-dst rank-1 accumulation + inline edge-MLP, cin=64 ----------------
// lane L: cg=L&7 (cols i0=cg*8..+7), mg=L>>3, m = mg*8+j.

__global__ __launch_bounds__(64) void k_accK2(const float* __restrict__ x1, const int* __restrict__ src,
    const int* __restrict__ offs, const int* __restrict__ elist,
    const float* __restrict__ ea, const float* __restrict__ w1, const float* __restrict__ b1,
    unsigned short* __restrict__ K, float* __restrict__ XS, int v0){
  int v = v0 + blockIdx.x;
  int L = threadIdx.x;
  int cg = L & 7, mg = L >> 3;
  int i0 = cg << 3;
  float w1c0 = w1[L], w1c1 = w1[64+L], w1c2 = w1[128+L], w1c3 = w1[192+L];
  float b1c = b1[L];
  __shared__ float sh[2][64];
  float acc[8][8];
  #pragma unroll
  for(int j=0;j<8;j++)
    #pragma unroll
    for(int c=0;c<8;c++) acc[j][c]=0.f;
  float4 xs0 = make_float4(0.f,0.f,0.f,0.f);
  float4 xs1 = make_float4(0.f,0.f,0.f,0.f);
  int p0 = offs[v], p1 = offs[v+1];
  float4 a_nxt = make_float4(0.f,0.f,0.f,0.f);
  float4 x_nxt0 = make_float4(0.f,0.f,0.f,0.f);
  float4 x_nxt1 = make_float4(0.f,0.f,0.f,0.f);
  if(p0 < p1){
    int e = elist[p0];
    a_nxt = *(const float4*)(ea + (size_t)e*4);
    const float* xr = x1 + (size_t)src[e]*64 + i0;
    x_nxt0 = *(const float4*)xr;
    x_nxt1 = *(const float4*)(xr+4);
  }
  for(int p=p0;p<p1;p++){
    int buf = (p-p0)&1;
    float4 xv0 = x_nxt0, xv1 = x_nxt1;
    float4 av = a_nxt;
    float hv = fmaxf(b1c + av.x*w1c0 + av.y*w1c1 + av.z*w1c2 + av.w*w1c3, 0.f);
    sh[buf][L] = hv;
    __syncthreads();
    if(p+1<p1){
      int e = elist[p+1];
      a_nxt = *(const float4*)(ea + (size_t)e*4);
      const float* xr = x1 + (size_t)src[e]*64 + i0;
      x_nxt0 = *(const float4*)xr;
      x_nxt1 = *(const float4*)(xr+4);
    }
    xs0.x += xv0.x; xs0.y += xv0.y; xs0.z += xv0.z; xs0.w += xv0.w;
    xs1.x += xv1.x; xs1.y += xv1.y; xs1.z += xv1.z; xs1.w += xv1.w;
    float4 h4a = *(float4*)&sh[buf][mg*8];
    float4 h4b = *(float4*)&sh[buf][mg*8+4];
    #pragma unroll
    for(int jj=0;jj<2;jj++){
      float4 h4 = jj? h4b : h4a;
      #pragma unroll
      for(int tq=0;tq<4;tq++){
        int j = jj*4+tq;
        float hm = (tq==0)?h4.x:(tq==1)?h4.y:(tq==2)?h4.z:h4.w;
        acc[j][0] += hm*xv0.x; acc[j][1] += hm*xv0.y;
        acc[j][2] += hm*xv0.z; acc[j][3] += hm*xv0.w;
        acc[j][4] += hm*xv1.x; acc[j][5] += hm*xv1.y;
        acc[j][6] += hm*xv1.z; acc[j][7] += hm*xv1.w;
      }
    }
  }
  unsigned short* Kv = K + (size_t)blockIdx.x*4096;
  #pragma unroll
  for(int j=0;j<8;j++){
    int m = mg*8 + j;
    u16x8 u;
    #pragma unroll
    for(int c=0;c<8;c++) u[c] = f2b(acc[j][c]);
    *(u16x8*)(Kv + m*64 + i0) = u;
  }
  if(mg==0){
    *(float4*)(XS + (size_t)v*64 + i0)     = xs0;
    *(float4*)(XS + (size_t)v*64 + i0 + 4) = xs1;
  }
}

// ---------------- MFMA split-K GEMM with register-prefetch double buffering ----------------

#define GBK 64

__global__ __launch_bounds__(256) void k_gemm(const unsigned short* __restrict__ A,
    const unsigned short* __restrict__ Bt, float* __restrict__ P,
    int rows, int Ktot, int Kc){
  __shared__ unsigned short As[128*72];
  __shared__ unsigned short Bs[64*72];
  int t = threadIdx.x;
  int lane = t & 63;
  int w = t >> 6;
  int row0 = blockIdx.x*128;
  int k0 = blockIdx.y*Kc;

  int srow  = t >> 3;
  int skseg = (t & 7) << 3;

  float4v acc[2][4];
  #pragma unroll
  for(int rt=0;rt<2;rt++)
    #pragma unroll
    for(int ct=0;ct<4;ct++)
      #pragma unroll
      for(int qq=0;qq<4;qq++) acc[rt][ct][qq]=0.f;

  int lrow = lane & 15;
  int lk   = (lane >> 4) << 3;

  short8 a_pf[4], b_pf[2];
  int T = Kc/GBK;

  {
    int kk = k0 + skseg;
    #pragma unroll
    for(int qq=0;qq<4;qq++){
      int gr = row0 + srow + 32*qq;
      short8 z = {0,0,0,0,0,0,0,0};
      a_pf[qq] = (gr<rows)? *(const short8*)(A + (size_t)gr*Ktot + kk) : z;
    }
    #pragma unroll
    for(int qq=0;qq<2;qq++){
      int o = srow + 32*qq;
      b_pf[qq] = *(const short8*)(Bt + (size_t)o*Ktot + kk);
    }
  }

  for(int tt=0; tt<T; tt++){
    __syncthreads();
    #pragma unroll
    for(int qq=0;qq<4;qq++)
      *(short8*)(As + (srow + 32*qq)*72 + skseg) = a_pf[qq];
    #pragma unroll
    for(int qq=0;qq<2;qq++)
      *(short8*)(Bs + (srow + 32*qq)*72 + skseg) = b_pf[qq];
    __syncthreads();
    if(tt+1 < T){
      int kk = k0 + (tt+1)*GBK + skseg;
      #pragma unroll
      for(int qq=0;qq<4;qq++){
        int gr = row0 + srow + 32*qq;
        short8 z = {0,0,0,0,0,0,0,0};
        a_pf[qq] = (gr<rows)? *(const short8*)(A + (size_t)gr*Ktot + kk) : z;
      }
      #pragma unroll
      for(int qq=0;qq<2;qq++){
        int o = srow + 32*qq;
        b_pf[qq] = *(const short8*)(Bt + (size_t)o*Ktot + kk);
      }
    }
    #pragma unroll
    for(int k32=0;k32<2;k32++){
      int kf = k32*32 + lk;
      short8 a0 = *(short8*)(As + (w*32      + lrow)*72 + kf);
      short8 a1 = *(short8*)(As + (w*32 + 16 + lrow)*72 + kf);
      #pragma unroll
      for(int ct=0;ct<4;ct++){
        short8 b = *(short8*)(Bs + (ct*16 + lrow)*72 + kf);
        acc[0][ct] = __builtin_amdgcn_mfma_f32_16x16x32_bf16(a0, b, acc[0][ct], 0,0,0);
        acc[1][ct] = __builtin_amdgcn_mfma_f32_16x16x32_bf16(a1, b, acc[1][ct], 0,0,0);
      }
    }
  }
  size_t base = (size_t)blockIdx.y*rows*64;
  int quad = lane >> 4;
  #pragma unroll
  for(int rt=0;rt<2;rt++){
    #pragma unroll
    for(int ct=0;ct<4;ct++){
      int c = ct*16 + lrow;
      #pragma unroll
      for(int reg=0;reg<4;reg++){
        int r = row0 + w*32 + rt*16 + quad*4 + reg;
        if(r < rows) P[base + (size_t)r*64 + c] = acc[rt][ct][reg];
      }
    }
  }
}

// ---------------- split reduction + epilogue (layer1 / fallback) ----------------

template<int CIN, int SPLIT>
__global__ __launch_bounds__(256) void k_reduce_ep(const float* __restrict__ P, int rows, int v0,
    const float* __restrict__ XS, const float* __restrict__ b2, const float* __restrict__ xprev,
    const float* __restrict__ root, const float* __restrict__ bias, const int* __restrict__ offs,
    float* __restrict__ out){
  int idx = blockIdx.x*256 + threadIdx.x;
  if(idx >= rows*16) return;
  int r = idx >> 4, og = (idx & 15) << 2;
  int v = v0 + r;

  float4 s = make_float4(0.f,0.f,0.f,0.f);
  #pragma unroll
  for(int z=0; z<SPLIT; z++){
    float4 p = *(const float4*)(P + ((size_t)z*rows + r)*64 + og);
    s.x += p.x; s.y += p.y; s.z += p.z; s.w += p.w;
  }
  #pragma unroll
  for(int i=0;i<CIN;i++){
    float xsv = XS[(size_t)v*64 + i];
    float4 b = *(const float4*)(b2 + i*64 + og);
    s.x += xsv*b.x; s.y += xsv*b.y; s.z += xsv*b.z; s.w += xsv*b.w;
  }
  float4 rt = make_float4(0.f,0.f,0.f,0.f);
  #pragma unroll
  for(int i=0;i<CIN;i++){
    float xv = xprev[(size_t)v*CIN + i];
    float4 wv = *(const float4*)(root + i*64 + og);
    rt.x += xv*wv.x; rt.y += xv*wv.y; rt.z += xv*wv.z; rt.w += xv*wv.w;
  }
  float c = (float)(offs[v+1]-offs[v]); c = fmaxf(c, 1.f);
  float inv = 1.f/c;
  float4 bi = *(const float4*)(bias + og);
  float4 o;
  o.x = fmaxf(s.x*inv + rt.x + bi.x, 0.f);
  o.y = fmaxf(s.y*inv + rt.y + bi.y, 0.f);
  o.z = fmaxf(s.z*inv + rt.z + bi.z, 0.f);
  o.w = fmaxf(s.w*inv + rt.w + bi.w, 0.f);
  *(float4*)(out + (size_t)v*64 + og) = o;
}

// ---------------- layer-2 reduction + epilogue + fused readout ----------------

template<int SPLIT>
__global__ __launch_bounds__(256) void k_red2_ro(const float* __restrict__ P, int rows,
    const float* __restrict__ XS, const float* __restrict__ b2, const float* __restrict__ x1,
    const float* __restrict__ root, const float* __restrict__ bias, const int* __restrict__ offs,
    const float* __restrict__ lw1, const float* __restrict__ lb1,
    const float* __restrict__ lw2, const float* __restrict__ lb2,
    float* __restrict__ out){
  __shared__ float row[16][68];
  __shared__ float hjs[16][8];
  int tid = threadIdx.x;
  int idx = blockIdx.x*256 + tid;
  int r = idx >> 4, og = (idx & 15) << 2;
  int n = tid >> 4;
  int nbase = blockIdx.x*16;
  int ninblk = rows - nbase; if(ninblk > 16) ninblk = 16;

  float4 o = make_float4(0.f,0.f,0.f,0.f);
  if(r < rows){
    float4 s = make_float4(0.f,0.f,0.f,0.f);
    #pragma unroll
    for(int z=0; z<SPLIT; z++){
      float4 p = *(const float4*)(P + ((size_t)z*rows + r)*64 + og);
      s.x += p.x; s.y += p.y; s.z += p.z; s.w += p.w;
    }
    #pragma unroll
    for(int i=0;i<64;i++){
      float xsv = XS[(size_t)r*64 + i];
      float4 b = *(const float4*)(b2 + i*64 + og);
      s.x += xsv*b.x; s.y += xsv*b.y; s.z += xsv*b.z; s.w += xsv*b.w;
    }
    float4 rt = make_float4(0.f,0.f,0.f,0.f);
    #pragma unroll
    for(int i=0;i<64;i++){
      float xv = x1[(size_t)r*64 + i];
      float4 wv = *(const float4*)(root + i*64 + og);
      rt.x += xv*wv.x; rt.y += xv*wv.y; rt.z += xv*wv.z; rt.w += xv*wv.w;
    }
    float c = (float)(offs[r+1]-offs[r]); c = fmaxf(c, 1.f);
    float inv = 1.f/c;
    float4 bi = *(const float4*)(bias + og);
    o.x = fmaxf(s.x*inv + rt.x + bi.x, 0.f);
    o.y = fmaxf(s.y*inv + rt.y + bi.y, 0.f);
    o.z = fmaxf(s.z*inv + rt.z + bi.z, 0.f);
    o.w = fmaxf(s.w*inv + rt.w + bi.w, 0.f);
  }
  *(float4*)&row[n][og] = o;
  __syncthreads();
  if(tid < 128){
    int n2 = tid >> 3, j = tid & 7;
    if(n2 < ninblk){
      float a = lb1[j];
      #pragma unroll
      for(int i=0;i<64;i++) a += row[n2][i]*lw1[i*8+j];
      hjs[n2][j] = fmaxf(a, 0.f)*lw2[j];
    }
  }
  __syncthreads();
  if(tid < 16 && tid < ninblk){
    float s = lb2[0];
    #pragma unroll
    for(int j=0;j<8;j++) s += hjs[tid][j];
    out[nbase + tid] = s;
  }
}

// ---------------- readout (fallback path only) ----------------

__global__ void k_readout(const float* __restrict__ x2, const float* __restrict__ lw1,
                          const float* __restrict__ lb1, const float* __restrict__ lw2,
                          const float* __restrict__ lb2, float* __restrict__ out){
  int v = blockIdx.x*256 + threadIdx.x;
  if(v >= NN) return;
  float accj[8];
  #pragma unroll
  for(int j=0;j<8;j++) accj[j] = lb1[j];
  const float* xr = x2 + (size_t)v*64;
  #pragma unroll 16
  for(int i=0;i<64;i++){
    float xv = xr[i];
    #pragma unroll
    for(int j=0;j<8;j++) accj[j] += xv*lw1[i*8+j];
  }
  float o = lb2[0];
  #pragma unroll
  for(int j=0;j<8;j++) o += fmaxf(accj[j],0.f)*lw2[j];
  out[v] = o;
}

// ---------------- host ----------------

extern "C" void kernel_launch(void* const* d_in, const int* in_sizes, int n_in,
                              void* d_out, int out_size, void* d_ws, size_t ws_size,
                              hipStream_t stream) {
  const float* x      = (const float*)d_in[0];
  const int*   ei     = (const int*)d_in[1];
  const float* ea     = (const float*)d_in[2];
  const float* nn1_w1 = (const float*)d_in[3];
  const float* nn1_b1 = (const float*)d_in[4];
  const float* nn1_w2 = (const float*)d_in[5];
  const float* nn1_b2 = (const float*)d_in[6];
  const float* root1  = (const float*)d_in[7];
  const float* bias1  = (const float*)d_in[8];
  const float* nn2_w1 = (const float*)d_in[9];
  const float* nn2_b1 = (const float*)d_in[10];
  const float* nn2_w2 = (const float*)d_in[11];
  const float* nn2_b2 = (const float*)d_in[12];
  const float* root2  = (const float*)d_in[13];
  const float* bias2  = (const float*)d_in[14];
  const float* lin1_w = (const float*)d_in[15];
  const float* lin1_b = (const float*)d_in[16];
  const float* lin2_w = (const float*)d_in[17];
  const float* lin2_b = (const float*)d_in[18];
  float* out = (float*)d_out;

  const int* srcIdx = ei;
  const int* dstIdx = ei + EE;

  char* w = (char*)d_ws;
  size_t off = 0;
  auto alloc = [&](size_t bytes)->void*{
    void* p = w + off;
    off = (off + bytes + 255) & ~(size_t)255;
    return p;
  };
  int*            cnt    = (int*)           alloc((size_t)NN*4);
  int*            offs   = (int*)           alloc((size_t)(NN+1)*4);
  int*            cursor = (int*)           alloc((size_t)NN*4);
  int*            elist  = (int*)           alloc((size_t)EE*4);
  float*          XS     = (float*)         alloc((size_t)NN*64*4);
  float*          x1     = (float*)         alloc((size_t)NN*64*4);
  unsigned short* Bt1    = (unsigned short*)alloc((size_t)64*1024*2);
  unsigned short* Bt2    = (unsigned short*)alloc((size_t)64*4096*2);
  size_t fixedBytes = off;
  size_t R = (ws_size > fixedBytes) ? (ws_size - fixedBytes) : 0;

  const int S1 = 4, S2 = 8;
  size_t needSingle = (size_t)NN*4096*2 + (size_t)S2*NN*64*4;
  bool single = (R >= needSingle + 4096);

  k_prep   <<<1320, 256, 0, stream>>>(nn1_w2, Bt1, nn2_w2, Bt2, cnt);
  k_hist   <<<(EE+255)/256, 256, 0, stream>>>(dstIdx, cnt);
  k_scan   <<<1, 1024, 0, stream>>>(cnt, offs, cursor);
  k_scatter<<<(EE+255)/256, 256, 0, stream>>>(dstIdx, cursor, elist);

  if(single){
    unsigned short* Kbuf = (unsigned short*)(w + off);
    float* P = (float*)(w + off + (size_t)NN*4096*2);

    k_accK1<<<NN, 64, 0, stream>>>(x, srcIdx, offs, elist, ea, nn1_w1, nn1_b1, Kbuf, XS, 0);
    {
      dim3 g((NN+127)/128, S1);
      k_gemm<<<g, 256, 0, stream>>>(Kbuf, Bt1, P, NN, 1024, 1024/S1);
    }
    k_reduce_ep<16,S1><<<(NN*16+255)/256, 256, 0, stream>>>(P, NN, 0, XS, nn1_b2, x,
                                                             root1, bias1, offs, x1);
    k_accK2<<<NN, 64, 0, stream>>>(x1, srcIdx, offs, elist, ea, nn2_w1, nn2_b1, Kbuf, XS, 0);
    {
      dim3 g((NN+127)/128, S2);
      k_gemm<<<g, 256, 0, stream>>>(Kbuf, Bt2, P, NN, 4096, 4096/S2);
    }
    k_red2_ro<S2><<<(NN+15)/16, 256, 0, stream>>>(P, NN, XS, nn2_b2, x1, root2, bias2, offs,
                                                   lin1_w, lin1_b, lin2_w, lin2_b, out);
  } else {
    float* x2b = (float*)alloc((size_t)NN*64*4);
    R = (ws_size > off) ? (ws_size - off) : 0;
    long long C2 = (long long)(R / (4096*2 + S2*64*4));
    long long C1 = (long long)(R / (1024*2 + S1*64*4));
    if(C2 > NN) C2 = NN; if(C1 > NN) C1 = NN;
    if(C2 < 128) C2 = 128; if(C1 < 128) C1 = 128;
    unsigned short* Kbuf = (unsigned short*)(w + off);
    {
      float* P = (float*)(w + off + (size_t)C1*1024*2);
      for(long long v0=0; v0<NN; v0+=C1){
        int rows = (int)((NN - v0 < C1) ? (NN - v0) : C1);
        k_accK1<<<rows, 64, 0, stream>>>(x, srcIdx, offs, elist, ea, nn1_w1, nn1_b1, Kbuf, XS, (int)v0);
        dim3 g((rows+127)/128, S1);
        k_gemm<<<g, 256, 0, stream>>>(Kbuf, Bt1, P, rows, 1024, 1024/S1);
        k_reduce_ep<16,S1><<<(rows*16+255)/256, 256, 0, stream>>>(P, rows, (int)v0, XS, nn1_b2, x,
                                                                   root1, bias1, offs, x1);
      }
    }
    {
      float* P = (float*)(w + off + (size_t)C2*4096*2);
      for(long long v0=0; v0<NN; v0+=C2){
        int rows = (int)((NN - v0 < C2) ? (NN - v0) : C2);
        k_accK2<<<rows, 64, 0, stream>>>(x1, srcIdx, offs, elist, ea, nn2_w1, nn2_b1, Kbuf, XS, (int)v0);
        dim3 g((rows+127)/128, S2);
        k_gemm<<<g, 256, 0, stream>>>(Kbuf, Bt2, P, rows, 4096, 4096/S2);
        k_reduce_ep<64,S2><<<(rows*16+255)/256, 256, 0, stream>>>(P, rows, (int)v0, XS, nn2_b2, x1,
                                                                   root2, bias2, offs, x2b);
      }
    }
    k_readout<<<(NN+255)/256, 256, 0, stream>>>(x2b, lin1_w, lin1_b, lin2_w, lin2_b, out);
  }
}

// Round 9
// 205.840 us; speedup vs baseline: 1.2290x; 1.0278x over previous
//
#include <hip/hip_runtime.h>
#include <hip/hip_bf16.h>

#define NN 10000
#define EE 65536

using short8  = __attribute__((ext_vector_type(8))) short;
using u16x8   = __attribute__((ext_vector_type(8))) unsigned short;
using float4v = __attribute__((ext_vector_type(4))) float;

__device__ __forceinline__ unsigned short f2b(float f){
  union { float f; unsigned int u; } v; v.f = f;
  unsigned int u = v.u;
  unsigned int r = (u + 0x7fff + ((u >> 16) & 1)) >> 16;  // RNE
  return (unsigned short)r;
}

// ---------------- prep: zero cnt + permB x2 (bf16 transposed weights) ----------------
// blocks: [0,40) zero cnt | [40,296) permB1 | [296,1320) permB2

__device__ __forceinline__ void do_permB(int idx, const float* __restrict__ w2,
                                         unsigned short* __restrict__ Bt, int cin){
  int K = cin*64;
  int o = idx / K;
  int k = idx - o*K;
  int m = k / cin;
  int i = k - m*cin;
  Bt[idx] = f2b(w2[(size_t)m*(cin*64) + i*64 + o]);
}

__global__ __launch_bounds__(256) void k_prep(
    const float* __restrict__ w2a, unsigned short* __restrict__ Bt1,
    const float* __restrict__ w2b, unsigned short* __restrict__ Bt2,
    int* __restrict__ cnt){
  int b = blockIdx.x;
  int t = threadIdx.x;
  if(b < 40){
    int i = b*256 + t;
    if(i < NN) cnt[i] = 0;
  } else if(b < 296){
    do_permB((b-40)*256 + t, w2a, Bt1, 16);
  } else {
    do_permB((b-296)*256 + t, w2b, Bt2, 64);
  }
}

// ---------------- CSR build (multi-block; lesson R6: parallelism >> dispatch count) ----------------

__global__ void k_hist(const int* __restrict__ dst, int* __restrict__ cnt){
  int e = blockIdx.x*256 + threadIdx.x;
  if(e < EE) atomicAdd(&cnt[dst[e]], 1);
}

__global__ __launch_bounds__(1024) void k_scan(const int* __restrict__ cnt, int* __restrict__ offs, int* __restrict__ cursor){
  const int T = 1024, PER = (NN + T - 1)/T; // 10
  int tid = threadIdx.x;
  int base = tid*PER;
  int local[PER];
  int s = 0;
  #pragma unroll
  for(int j=0;j<PER;j++){
    int i = base+j;
    int v = (i<NN)? cnt[i] : 0;
    local[j] = s;
    s += v;
  }
  int lane = tid & 63, wv = tid >> 6;
  int val = s;
  #pragma unroll
  for(int o=1;o<64;o<<=1){
    int u = __shfl_up(val, o, 64);
    if(lane >= o) val += u;
  }
  __shared__ int wsum[16];
  if(lane==63) wsum[wv] = val;
  __syncthreads();
  if(tid==0){
    int acc=0;
    #pragma unroll
    for(int i=0;i<16;i++){ int t2=wsum[i]; wsum[i]=acc; acc+=t2; }
  }
  __syncthreads();
  int thr_excl = wsum[wv] + (val - s);
  #pragma unroll
  for(int j=0;j<PER;j++){
    int i = base+j;
    if(i<NN){ int e = thr_excl + local[j]; offs[i]=e; cursor[i]=e; }
  }
  if(tid == T-1) offs[NN] = thr_excl + s;
}

// scatter writes (e, src[e]) so accK's load chain is one level shorter
__global__ void k_scatter(const int* __restrict__ dst, const int* __restrict__ src,
                          int* __restrict__ cursor, int2* __restrict__ elist2){
  int e = blockIdx.x*256 + threadIdx.x;
  if(e < EE){ int p = atomicAdd(&cursor[dst[e]], 1); elist2[p] = make_int2(e, src[e]); }
}

// ---------------- per-dst rank-1 accumulation + inline edge-MLP, cin=16 ----------------

__global__ __launch_bounds__(64) void k_accK1(const float* __restrict__ x,
    const int* __restrict__ offs, const int2* __restrict__ elist2,
    const float* __restrict__ ea, const float* __restrict__ w1, const float* __restrict__ b1,
    unsigned short* __restrict__ K1, float* __restrict__ XS, int v0){
  int v = v0 + blockIdx.x;
  int L = threadIdx.x;
  int cg = L & 3, mg = L >> 2;
  int i0 = cg << 2;
  float w1c0 = w1[L], w1c1 = w1[64+L], w1c2 = w1[128+L], w1c3 = w1[192+L];
  float b1c = b1[L];
  __shared__ float sh[2][64];
  float acc[4][4];
  #pragma unroll
  for(int j=0;j<4;j++)
    #pragma unroll
    for(int c=0;c<4;c++) acc[j][c]=0.f;
  float4 xs = make_float4(0.f,0.f,0.f,0.f);
  int p0 = offs[v], p1 = offs[v+1];
  float4 a_nxt = make_float4(0.f,0.f,0.f,0.f);
  float4 x_nxt = make_float4(0.f,0.f,0.f,0.f);
  if(p0 < p1){
    int2 es = elist2[p0];
    a_nxt = *(const float4*)(ea + (size_t)es.x*4);
    x_nxt = *(const float4*)(x + (size_t)es.y*16 + i0);
  }
  for(int p=p0;p<p1;p++){
    int buf = (p-p0)&1;
    float4 xv = x_nxt;
    float4 av = a_nxt;
    float hv = fmaxf(b1c + av.x*w1c0 + av.y*w1c1 + av.z*w1c2 + av.w*w1c3, 0.f);
    sh[buf][L] = hv;
    __syncthreads();
    if(p+1<p1){
      int2 es = elist2[p+1];
      a_nxt = *(const float4*)(ea + (size_t)es.x*4);
      x_nxt = *(const float4*)(x + (size_t)es.y*16 + i0);
    }
    xs.x += xv.x; xs.y += xv.y; xs.z += xv.z; xs.w += xv.w;
    #pragma unroll
    for(int j=0;j<4;j++){
      float hm = sh[buf][mg + 16*j];
      acc[j][0] += hm*xv.x; acc[j][1] += hm*xv.y;
      acc[j][2] += hm*xv.z; acc[j][3] += hm*xv.w;
    }
  }
  unsigned short* Kv = K1 + (size_t)blockIdx.x*1024;
  #pragma unroll
  for(int j=0;j<4;j++){
    int m = mg + 16*j;
    ushort4 u;
    u.x=f2b(acc[j][0]); u.y=f2b(acc[j][1]); u.z=f2b(acc[j][2]); u.w=f2b(acc[j][3]);
    *(ushort4*)(Kv + m*16 + i0) = u;
  }
  if(mg==0) *(float4*)(XS + (size_t)v*64 + i0) = xs;
}

// ---------------- per-dst rank-1 accumulation + inline edge-MLP, cin=64 ----------------

__global__ __launch_bounds__(64) void k_accK2(const float* __restrict__ x1,
    const int* __restrict__ offs, const int2* __restrict__ elist2,
    const float* __restrict__ ea, const float* __restrict__ w1, const float* __restrict__ b1,
    unsigned short* __restrict__ K, float* __restrict__ XS, int v0){
  int v = v0 + blockIdx.x;
  int L = threadIdx.x;
  int cg = L & 7, mg = L >> 3;
  int i0 = cg << 3;
  float w1c0 = w1[L], w1c1 = w1[64+L], w1c2 = w1[128+L], w1c3 = w1[192+L];
  float b1c = b1[L];
  __shared__ float sh[2][64];
  float acc[8][8];
  #pragma unroll
  for(int j=0;j<8;j++)
    #pragma unroll
    for(int c=0;c<8;c++) acc[j][c]=0.f;
  float4 xs0 = make_float4(0.f,0.f,0.f,0.f);
  float4 xs1 = make_float4(0.f,0.f,0.f,0.f);
  int p0 = offs[v], p1 = offs[v+1];
  float4 a_nxt = make_float4(0.f,0.f,0.f,0.f);
  float4 x_nxt0 = make_float4(0.f,0.f,0.f,0.f);
  float4 x_nxt1 = make_float4(0.f,0.f,0.f,0.f);
  if(p0 < p1){
    int2 es = elist2[p0];
    a_nxt = *(const float4*)(ea + (size_t)es.x*4);
    const float* xr = x1 + (size_t)es.y*64 + i0;
    x_nxt0 = *(const float4*)xr;
    x_nxt1 = *(const float4*)(xr+4);
  }
  for(int p=p0;p<p1;p++){
    int buf = (p-p0)&1;
    float4 xv0 = x_nxt0, xv1 = x_nxt1;
    float4 av = a_nxt;
    float hv = fmaxf(b1c + av.x*w1c0 + av.y*w1c1 + av.z*w1c2 + av.w*w1c3, 0.f);
    sh[buf][L] = hv;
    __syncthreads();
    if(p+1<p1){
      int2 es = elist2[p+1];
      a_nxt = *(const float4*)(ea + (size_t)es.x*4);
      const float* xr = x1 + (size_t)es.y*64 + i0;
      x_nxt0 = *(const float4*)xr;
      x_nxt1 = *(const float4*)(xr+4);
    }
    xs0.x += xv0.x; xs0.y += xv0.y; xs0.z += xv0.z; xs0.w += xv0.w;
    xs1.x += xv1.x; xs1.y += xv1.y; xs1.z += xv1.z; xs1.w += xv1.w;
    float4 h4a = *(float4*)&sh[buf][mg*8];
    float4 h4b = *(float4*)&sh[buf][mg*8+4];
    #pragma unroll
    for(int jj=0;jj<2;jj++){
      float4 h4 = jj? h4b : h4a;
      #pragma unroll
      for(int tq=0;tq<4;tq++){
        int j = jj*4+tq;
        float hm = (tq==0)?h4.x:(tq==1)?h4.y:(tq==2)?h4.z:h4.w;
        acc[j][0] += hm*xv0.x; acc[j][1] += hm*xv0.y;
        acc[j][2] += hm*xv0.z; acc[j][3] += hm*xv0.w;
        acc[j][4] += hm*xv1.x; acc[j][5] += hm*xv1.y;
        acc[j][6] += hm*xv1.z; acc[j][7] += hm*xv1.w;
      }
    }
  }
  unsigned short* Kv = K + (size_t)blockIdx.x*4096;
  #pragma unroll
  for(int j=0;j<8;j++){
    int m = mg*8 + j;
    u16x8 u;
    #pragma unroll
    for(int c=0;c<8;c++) u[c] = f2b(acc[j][c]);
    *(u16x8*)(Kv + m*64 + i0) = u;
  }
  if(mg==0){
    *(float4*)(XS + (size_t)v*64 + i0)     = xs0;
    *(float4*)(XS + (size_t)v*64 + i0 + 4) = xs1;
  }
}

// ---------------- MFMA split-K GEMM: 64-row tiles for 2.4x more blocks/TLP ----------------
// block: 64 rows x 64 cols, 256 threads = 4 waves; wave w owns rows [w*16, w*16+16).

#define GBK 64

__global__ __launch_bounds__(256) void k_gemm(const unsigned short* __restrict__ A,
    const unsigned short* __restrict__ Bt, float* __restrict__ P,
    int rows, int Ktot, int Kc){
  __shared__ unsigned short As[64*72];
  __shared__ unsigned short Bs[64*72];
  int t = threadIdx.x;
  int lane = t & 63;
  int w = t >> 6;
  int row0 = blockIdx.x*64;
  int k0 = blockIdx.y*Kc;

  int srow  = t >> 3;        // 0..31
  int skseg = (t & 7) << 3;  // elem 0,8,...,56

  float4v acc[4];
  #pragma unroll
  for(int ct=0;ct<4;ct++)
    #pragma unroll
    for(int qq=0;qq<4;qq++) acc[ct][qq]=0.f;

  int lrow = lane & 15;
  int lk   = (lane >> 4) << 3;

  short8 a_pf[2], b_pf[2];
  int T = Kc/GBK;

  {
    int kk = k0 + skseg;
    #pragma unroll
    for(int qq=0;qq<2;qq++){
      int gr = row0 + srow + 32*qq;
      short8 z = {0,0,0,0,0,0,0,0};
      a_pf[qq] = (gr<rows)? *(const short8*)(A + (size_t)gr*Ktot + kk) : z;
      int o = srow + 32*qq;
      b_pf[qq] = *(const short8*)(Bt + (size_t)o*Ktot + kk);
    }
  }

  for(int tt=0; tt<T; tt++){
    __syncthreads();
    #pragma unroll
    for(int qq=0;qq<2;qq++){
      *(short8*)(As + (srow + 32*qq)*72 + skseg) = a_pf[qq];
      *(short8*)(Bs + (srow + 32*qq)*72 + skseg) = b_pf[qq];
    }
    __syncthreads();
    if(tt+1 < T){
      int kk = k0 + (tt+1)*GBK + skseg;
      #pragma unroll
      for(int qq=0;qq<2;qq++){
        int gr = row0 + srow + 32*qq;
        short8 z = {0,0,0,0,0,0,0,0};
        a_pf[qq] = (gr<rows)? *(const short8*)(A + (size_t)gr*Ktot + kk) : z;
        int o = srow + 32*qq;
        b_pf[qq] = *(const short8*)(Bt + (size_t)o*Ktot + kk);
      }
    }
    #pragma unroll
    for(int k32=0;k32<2;k32++){
      int kf = k32*32 + lk;
      short8 a0 = *(short8*)(As + (w*16 + lrow)*72 + kf);
      #pragma unroll
      for(int ct=0;ct<4;ct++){
        short8 b = *(short8*)(Bs + (ct*16 + lrow)*72 + kf);
        acc[ct] = __builtin_amdgcn_mfma_f32_16x16x32_bf16(a0, b, acc[ct], 0,0,0);
      }
    }
  }
  size_t base = (size_t)blockIdx.y*rows*64;
  int quad = lane >> 4;
  #pragma unroll
  for(int ct=0;ct<4;ct++){
    int c = ct*16 + lrow;
    #pragma unroll
    for(int reg=0;reg<4;reg++){
      int r = row0 + w*16 + quad*4 + reg;
      if(r < rows) P[base + (size_t)r*64 + c] = acc[ct][reg];
    }
  }
}

// ---------------- split reduction + epilogue (layer1 / fallback) ----------------

template<int CIN, int SPLIT>
__global__ __launch_bounds__(256) void k_reduce_ep(const float* __restrict__ P, int rows, int v0,
    const float* __restrict__ XS, const float* __restrict__ b2, const float* __restrict__ xprev,
    const float* __restrict__ root, const float* __restrict__ bias, const int* __restrict__ offs,
    float* __restrict__ out){
  int idx = blockIdx.x*256 + threadIdx.x;
  if(idx >= rows*16) return;
  int r = idx >> 4, og = (idx & 15) << 2;
  int v = v0 + r;

  float4 s = make_float4(0.f,0.f,0.f,0.f);
  #pragma unroll
  for(int z=0; z<SPLIT; z++){
    float4 p = *(const float4*)(P + ((size_t)z*rows + r)*64 + og);
    s.x += p.x; s.y += p.y; s.z += p.z; s.w += p.w;
  }
  #pragma unroll
  for(int i=0;i<CIN;i++){
    float xsv = XS[(size_t)v*64 + i];
    float4 b = *(const float4*)(b2 + i*64 + og);
    s.x += xsv*b.x; s.y += xsv*b.y; s.z += xsv*b.z; s.w += xsv*b.w;
  }
  float4 rt = make_float4(0.f,0.f,0.f,0.f);
  #pragma unroll
  for(int i=0;i<CIN;i++){
    float xv = xprev[(size_t)v*CIN + i];
    float4 wv = *(const float4*)(root + i*64 + og);
    rt.x += xv*wv.x; rt.y += xv*wv.y; rt.z += xv*wv.z; rt.w += xv*wv.w;
  }
  float c = (float)(offs[v+1]-offs[v]); c = fmaxf(c, 1.f);
  float inv = 1.f/c;
  float4 bi = *(const float4*)(bias + og);
  float4 o;
  o.x = fmaxf(s.x*inv + rt.x + bi.x, 0.f);
  o.y = fmaxf(s.y*inv + rt.y + bi.y, 0.f);
  o.z = fmaxf(s.z*inv + rt.z + bi.z, 0.f);
  o.w = fmaxf(s.w*inv + rt.w + bi.w, 0.f);
  *(float4*)(out + (size_t)v*64 + og) = o;
}

// ---------------- layer-2 reduction + epilogue + fused readout ----------------

template<int SPLIT>
__global__ __launch_bounds__(256) void k_red2_ro(const float* __restrict__ P, int rows,
    const float* __restrict__ XS, const float* __restrict__ b2, const float* __restrict__ x1,
    const float* __restrict__ root, const float* __restrict__ bias, const int* __restrict__ offs,
    const float* __restrict__ lw1, const float* __restrict__ lb1,
    const float* __restrict__ lw2, const float* __restrict__ lb2,
    float* __restrict__ out){
  __shared__ float row[16][68];
  __shared__ float hjs[16][8];
  int tid = threadIdx.x;
  int idx = blockIdx.x*256 + tid;
  int r = idx >> 4, og = (idx & 15) << 2;
  int n = tid >> 4;
  int nbase = blockIdx.x*16;
  int ninblk = rows - nbase; if(ninblk > 16) ninblk = 16;

  float4 o = make_float4(0.f,0.f,0.f,0.f);
  if(r < rows){
    float4 s = make_float4(0.f,0.f,0.f,0.f);
    #pragma unroll
    for(int z=0; z<SPLIT; z++){
      float4 p = *(const float4*)(P + ((size_t)z*rows + r)*64 + og);
      s.x += p.x; s.y += p.y; s.z += p.z; s.w += p.w;
    }
    #pragma unroll
    for(int i=0;i<64;i++){
      float xsv = XS[(size_t)r*64 + i];
      float4 b = *(const float4*)(b2 + i*64 + og);
      s.x += xsv*b.x; s.y += xsv*b.y; s.z += xsv*b.z; s.w += xsv*b.w;
    }
    float4 rt = make_float4(0.f,0.f,0.f,0.f);
    #pragma unroll
    for(int i=0;i<64;i++){
      float xv = x1[(size_t)r*64 + i];
      float4 wv = *(const float4*)(root + i*64 + og);
      rt.x += xv*wv.x; rt.y += xv*wv.y; rt.z += xv*wv.z; rt.w += xv*wv.w;
    }
    float c = (float)(offs[r+1]-offs[r]); c = fmaxf(c, 1.f);
    float inv = 1.f/c;
    float4 bi = *(const float4*)(bias + og);
    o.x = fmaxf(s.x*inv + rt.x + bi.x, 0.f);
    o.y = fmaxf(s.y*inv + rt.y + bi.y, 0.f);
    o.z = fmaxf(s.z*inv + rt.z + bi.z, 0.f);
    o.w = fmaxf(s.w*inv + rt.w + bi.w, 0.f);
  }
  *(float4*)&row[n][og] = o;
  __syncthreads();
  if(tid < 128){
    int n2 = tid >> 3, j = tid & 7;
    if(n2 < ninblk){
      float a = lb1[j];
      #pragma unroll
      for(int i=0;i<64;i++) a += row[n2][i]*lw1[i*8+j];
      hjs[n2][j] = fmaxf(a, 0.f)*lw2[j];
    }
  }
  __syncthreads();
  if(tid < 16 && tid < ninblk){
    float s = lb2[0];
    #pragma unroll
    for(int j=0;j<8;j++) s += hjs[tid][j];
    out[nbase + tid] = s;
  }
}

// ---------------- readout (fallback path only) ----------------

__global__ void k_readout(const float* __restrict__ x2, const float* __restrict__ lw1,
                          const float* __restrict__ lb1, const float* __restrict__ lw2,
                          const float* __restrict__ lb2, float* __restrict__ out){
  int v = blockIdx.x*256 + threadIdx.x;
  if(v >= NN) return;
  float accj[8];
  #pragma unroll
  for(int j=0;j<8;j++) accj[j] = lb1[j];
  const float* xr = x2 + (size_t)v*64;
  #pragma unroll 16
  for(int i=0;i<64;i++){
    float xv = xr[i];
    #pragma unroll
    for(int j=0;j<8;j++) accj[j] += xv*lw1[i*8+j];
  }
  float o = lb2[0];
  #pragma unroll
  for(int j=0;j<8;j++) o += fmaxf(accj[j],0.f)*lw2[j];
  out[v] = o;
}

// ---------------- host ----------------

extern "C" void kernel_launch(void* const* d_in, const int* in_sizes, int n_in,
                              void* d_out, int out_size, void* d_ws, size_t ws_size,
                              hipStream_t stream) {
  const float* x      = (const float*)d_in[0];
  const int*   ei     = (const int*)d_in[1];
  const float* ea     = (const float*)d_in[2];
  const float* nn1_w1 = (const float*)d_in[3];
  const float* nn1_b1 = (const float*)d_in[4];
  const float* nn1_w2 = (const float*)d_in[5];
  const float* nn1_b2 = (const float*)d_in[6];
  const float* root1  = (const float*)d_in[7];
  const float* bias1  = (const float*)d_in[8];
  const float* nn2_w1 = (const float*)d_in[9];
  const float* nn2_b1 = (const float*)d_in[10];
  const float* nn2_w2 = (const float*)d_in[11];
  const float* nn2_b2 = (const float*)d_in[12];
  const float* root2  = (const float*)d_in[13];
  const float* bias2  = (const float*)d_in[14];
  const float* lin1_w = (const float*)d_in[15];
  const float* lin1_b = (const float*)d_in[16];
  const float* lin2_w = (const float*)d_in[17];
  const float* lin2_b = (const float*)d_in[18];
  float* out = (float*)d_out;

  const int* srcIdx = ei;
  const int* dstIdx = ei + EE;

  char* w = (char*)d_ws;
  size_t off = 0;
  auto alloc = [&](size_t bytes)->void*{
    void* p = w + off;
    off = (off + bytes + 255) & ~(size_t)255;
    return p;
  };
  int*            cnt    = (int*)           alloc((size_t)NN*4);
  int*            offs   = (int*)           alloc((size_t)(NN+1)*4);
  int*            cursor = (int*)           alloc((size_t)NN*4);
  int2*           elist2 = (int2*)          alloc((size_t)EE*8);
  float*          XS     = (float*)         alloc((size_t)NN*64*4);
  float*          x1     = (float*)         alloc((size_t)NN*64*4);
  unsigned short* Bt1    = (unsigned short*)alloc((size_t)64*1024*2);
  unsigned short* Bt2    = (unsigned short*)alloc((size_t)64*4096*2);
  size_t fixedBytes = off;
  size_t R = (ws_size > fixedBytes) ? (ws_size - fixedBytes) : 0;

  const int S1 = 4, S2 = 8;
  size_t needSingle = (size_t)NN*4096*2 + (size_t)S2*NN*64*4;
  bool single = (R >= needSingle + 4096);

  k_prep   <<<1320, 256, 0, stream>>>(nn1_w2, Bt1, nn2_w2, Bt2, cnt);
  k_hist   <<<(EE+255)/256, 256, 0, stream>>>(dstIdx, cnt);
  k_scan   <<<1, 1024, 0, stream>>>(cnt, offs, cursor);
  k_scatter<<<(EE+255)/256, 256, 0, stream>>>(dstIdx, srcIdx, cursor, elist2);

  if(single){
    unsigned short* Kbuf = (unsigned short*)(w + off);
    float* P = (float*)(w + off + (size_t)NN*4096*2);

    k_accK1<<<NN, 64, 0, stream>>>(x, offs, elist2, ea, nn1_w1, nn1_b1, Kbuf, XS, 0);
    {
      dim3 g((NN+63)/64, S1);
      k_gemm<<<g, 256, 0, stream>>>(Kbuf, Bt1, P, NN, 1024, 1024/S1);
    }
    k_reduce_ep<16,S1><<<(NN*16+255)/256, 256, 0, stream>>>(P, NN, 0, XS, nn1_b2, x,
                                                             root1, bias1, offs, x1);
    k_accK2<<<NN, 64, 0, stream>>>(x1, offs, elist2, ea, nn2_w1, nn2_b1, Kbuf, XS, 0);
    {
      dim3 g((NN+63)/64, S2);
      k_gemm<<<g, 256, 0, stream>>>(Kbuf, Bt2, P, NN, 4096, 4096/S2);
    }
    k_red2_ro<S2><<<(NN+15)/16, 256, 0, stream>>>(P, NN, XS, nn2_b2, x1, root2, bias2, offs,
                                                   lin1_w, lin1_b, lin2_w, lin2_b, out);
  } else {
    float* x2b = (float*)alloc((size_t)NN*64*4);
    R = (ws_size > off) ? (ws_size - off) : 0;
    long long C2 = (long long)(R / (4096*2 + S2*64*4));
    long long C1 = (long long)(R / (1024*2 + S1*64*4));
    if(C2 > NN) C2 = NN; if(C1 > NN) C1 = NN;
    if(C2 < 128) C2 = 128; if(C1 < 128) C1 = 128;
    unsigned short* Kbuf = (unsigned short*)(w + off);
    {
      float* P = (float*)(w + off + (size_t)C1*1024*2);
      for(long long v0=0; v0<NN; v0+=C1){
        int rows = (int)((NN - v0 < C1) ? (NN - v0) : C1);
        k_accK1<<<rows, 64, 0, stream>>>(x, offs, elist2, ea, nn1_w1, nn1_b1, Kbuf, XS, (int)v0);
        dim3 g((rows+63)/64, S1);
        k_gemm<<<g, 256, 0, stream>>>(Kbuf, Bt1, P, rows, 1024, 1024/S1);
        k_reduce_ep<16,S1><<<(rows*16+255)/256, 256, 0, stream>>>(P, rows, (int)v0, XS, nn1_b2, x,
                                                                   root1, bias1, offs, x1);
      }
    }
    {
      float* P = (float*)(w + off + (size_t)C2*4096*2);
      for(long long v0=0; v0<NN; v0+=C2){
        int rows = (int)((NN - v0 < C2) ? (NN - v0) : C2);
        k_accK2<<<rows, 64, 0, stream>>>(x1, offs, elist2, ea, nn2_w1, nn2_b1, Kbuf, XS, (int)v0);
        dim3 g((rows+63)/64, S2);
        k_gemm<<<g, 256, 0, stream>>>(Kbuf, Bt2, P, rows, 4096, 4096/S2);
        k_reduce_ep<64,S2><<<(rows*16+255)/256, 256, 0, stream>>>(P, rows, (int)v0, XS, nn2_b2, x1,
                                                                   root2, bias2, offs, x2b);
      }
    }
    k_readout<<<(NN+255)/256, 256, 0, stream>>>(x2b, lin1_w, lin1_b, lin2_w, lin2_b, out);
  }
}